// Round 6
// baseline (272.932 us; speedup 1.0000x reference)
//
#include <hip/hip_runtime.h>

#define AS1 __attribute__((address_space(1)))
#define AS3 __attribute__((address_space(3)))

typedef _Float16 half_t;
typedef __attribute__((ext_vector_type(8))) _Float16 f16x8;  // 8 f16 = 4 VGPRs
typedef __attribute__((ext_vector_type(4))) float f32x4;

static constexpr int Bsz = 4096;   // batch
static constexpr int INs = 512;    // input features
static constexpr int Hs  = 1024;   // hidden
static constexpr int BM  = 128;    // batch rows per block
static constexpr int BH  = 32;     // h-cols per block (x4 gates = 128 eff cols)
static constexpr int BK  = 64;     // K-tile

static constexpr size_t XN  = (size_t)Bsz * INs;
static constexpr size_t HXN = (size_t)Bsz * Hs;
static constexpr size_t WXN = (size_t)4 * Hs * INs;
static constexpr size_t WHN = (size_t)4 * Hs * Hs;
static constexpr size_t OFF_X  = 0;
static constexpr size_t OFF_HX = XN;
static constexpr size_t OFF_WX = XN + HXN;
static constexpr size_t OFF_WH = XN + HXN + WXN;
static constexpr size_t TOT    = XN + HXN + WXN + WHN;   // 12,582,912 f16

__device__ __forceinline__ float sigm(float x) {
  return 1.0f / (1.0f + __expf(-x));
}
__device__ __forceinline__ float tanh_fast(float x) {
  const float e = __expf(2.0f * x);
  return 1.0f - 2.0f / (e + 1.0f);
}

// fp32 -> fp16 (RNE) of the four matmul operands into ws. Loop-free;
// grid covers TOT/8 chunks exactly.
__global__ __launch_bounds__(256)
void cvt_kernel(const float* __restrict__ x, const float* __restrict__ hx,
                const float* __restrict__ wx, const float* __restrict__ wh,
                half_t* __restrict__ ws) {
  const size_t cid = (size_t)blockIdx.x * 256 + threadIdx.x;
  const size_t e = cid * 8;
  const float* src; size_t off;
  if (e < OFF_HX)      { src = x;  off = e - OFF_X; }
  else if (e < OFF_WX) { src = hx; off = e - OFF_HX; }
  else if (e < OFF_WH) { src = wx; off = e - OFF_WX; }
  else                 { src = wh; off = e - OFF_WH; }
  const f32x4 a = *(const f32x4*)(src + off);
  const f32x4 b = *(const f32x4*)(src + off + 4);
  f16x8 o;
  o[0]=(half_t)a[0]; o[1]=(half_t)a[1]; o[2]=(half_t)a[2]; o[3]=(half_t)a[3];
  o[4]=(half_t)b[0]; o[5]=(half_t)b[1]; o[6]=(half_t)b[2]; o[7]=(half_t)b[3];
  *(f16x8*)(ws + e) = o;
}

// ---------------------------------------------------------------------------
// r6: 128x128 tile, TRUE 2-phase pipeline + LDS-traffic halving.
// Diagnosis (r0..r5): all structures ~80-90 us; per-CU pipe arithmetic at
// r0 geometry says MFMA floor ~21 us but LDS (reads+staging writes ~3.1k
// cyc/step) exceeds MFMA (~2.1k), and the 1-phase stage->drain->compute
// order leaves staging latency (L2 ~200-400, HBM ~900 cyc) fully exposed
// every step. Fix:
//  - A-operand: global -> REGISTERS with prefetch depth 1 (step t loads
//    A(t+1) into the alternate register set; the end-of-step syncthreads
//    vmcnt(0) drain lands ~2k cyc after issue -> latency hidden). Deletes
//    A's LDS writes and ds_reads: LDS pipe ~1.5k cyc/step -> MFMA-bound.
//    Per-wave A reads are 128B contiguous per row; same-A-panel blocks
//    (same blockIdx.x, ids == x mod 8) colocate on one XCD -> L2 hits.
//    (r4's failure was loading A in the CONSUMING step, latency exposed,
//    no prefetch set.)
//  - B: LDS double buffer (2 x 16 KB), stage tile t+1 at the TOP of step t
//    (T3 minimum-2-phase recipe), ONE __syncthreads per step. Its builtin
//    vmcnt(0)+lgkmcnt(0) drain is exactly the dbuf handoff.
//  - 4+ blocks/CU retained (32 KB LDS): cross-block wave overlap (m114)
//    fills residual stalls. All 24 steps unrolled; register-set parity is
//    static (afA/afB named sets, rule-20 safe).
// Wave tiling 2x2 unchanged; XOR-swizzled B layout unchanged (0 conflicts).
// Eff-col c -> gate (c>>4)&3, h = h0 + (c>>6)*16 + (c&15).
// ---------------------------------------------------------------------------

#define LOAD_A(dst, Ab, vA0, Ka, kA) do { \
  _Pragma("unroll") \
  for (int mt_ = 0; mt_ < 4; ++mt_) \
    _Pragma("unroll") \
    for (int kk_ = 0; kk_ < 2; ++kk_) \
      dst[mt_][kk_] = *(const f16x8*)((Ab) + (size_t)(mt_ * 16 * (Ka)) + (vA0) + (kA) + kk_ * 32); \
} while (0)

#define STAGE_B(buf, Wb, vB, kS) do { \
  _Pragma("unroll") \
  for (int i_ = 0; i_ < 4; ++i_) { \
    const int e_ = i_ * 32 + ldr; \
    __builtin_amdgcn_global_load_lds((AS1 void*)((Wb) + (vB)[i_] + (kS)), \
        (AS3 void*)(Bs[buf] + (e_ * 8 + ldc) * 8), 16, 0, 0); \
  } \
} while (0)

#define COMPUTE(RB, AF) do { \
  _Pragma("unroll") \
  for (int kk_ = 0; kk_ < 2; ++kk_) { \
    const int c8x_ = kk_ * 4 + grp; \
    f16x8 bf_[4]; \
    _Pragma("unroll") \
    for (int nt_ = 0; nt_ < 4; ++nt_) { \
      const int e_ = wc * 64 + nt_ * 16 + l15; \
      bf_[nt_] = *(const f16x8*)(Bs[RB] + (e_ * 8 + (c8x_ ^ (l15 & 7))) * 8); \
    } \
    _Pragma("unroll") \
    for (int mt_ = 0; mt_ < 4; ++mt_) \
      _Pragma("unroll") \
      for (int nt_ = 0; nt_ < 4; ++nt_) \
        acc[mt_][nt_] = __builtin_amdgcn_mfma_f32_16x16x32_f16( \
            AF[mt_][kk_], bf_[nt_], acc[mt_][nt_], 0, 0, 0); \
  } \
} while (0)

// One K-step: stage B(next) into Bs[RB^1], load A(next) into NXT regs,
// compute current from Bs[RB] x CUR, one barrier.
#define GSTEP(CUR, NXT, RB, Wb, vB, kS, Ab, vA0, Ka, kA) do { \
  STAGE_B((RB) ^ 1, Wb, vB, kS); \
  LOAD_A(NXT, Ab, vA0, Ka, kA); \
  COMPUTE(RB, CUR); \
  __syncthreads(); \
} while (0)

__global__ __launch_bounds__(256, 4)
void plstm_gemm(const half_t* __restrict__ xin,   // [B,IN]  f16
                const half_t* __restrict__ hxp,   // [B,H]   f16
                const float* __restrict__ cxp,    // [B,H]
                const half_t* __restrict__ wxh,   // [4H,IN] f16
                const float* __restrict__ biasp,  // [4H]
                const half_t* __restrict__ whh,   // [4H,H]  f16
                const float* __restrict__ timep,  // [B]
                const float* __restrict__ taup,   // [H]
                const float* __restrict__ sp,     // [H]
                const float* __restrict__ alphap, // [1]
                const float* __restrict__ rhop,   // [1]
                float* __restrict__ outp)         // [2,B,H] = hy ; cy
{
  // XOR-swizzled 16B-chunk layout: slot (row e, c8) holds global chunk c8^(e&7).
  __shared__ half_t Bs[2][BM * BK];   // 2 x 16 KB (B only; A lives in regs)

  const int tid  = threadIdx.x;
  const int w    = tid >> 6;
  const int lane = tid & 63;
  const int l15  = lane & 15;
  const int grp  = lane >> 4;
  const int wr   = w >> 1;
  const int wc   = w & 1;

  const int m0 = blockIdx.x * BM;
  const int h0 = blockIdx.y * BH;

  f32x4 acc[4][4] = {};              // [m-subtile][gate]
  f16x8 afA[4][2], afB[4][2];        // A fragment double set (static parity)

  const int ldr = tid >> 3;          // 0..31
  const int ldc = tid & 7;           // 16B chunk col 0..7
  const int gc8 = ldc ^ (ldr & 7);   // global-side swizzle chunk (per-thread const)

  // per-lane loop-invariant offsets
  const int vA0X = (wr * 64 + l15) * INs + grp * 8;   // A-frag base, phase X
  const int vA0H = (wr * 64 + l15) * Hs  + grp * 8;   // A-frag base, phase H
  int vBX[4], vBH[4];
  #pragma unroll
  for (int i = 0; i < 4; ++i) {
    const int e    = i * 32 + ldr;
    const int wrow = ((e >> 4) & 3) * Hs + h0 + ((e >> 6) << 4) + (e & 15);
    vBX[i] = wrow * INs + gc8 * 8;
    vBH[i] = wrow * Hs  + gc8 * 8;
  }

  const half_t* xb = xin + (size_t)m0 * INs;   // uniform A base, phase X
  const half_t* hb = hxp + (size_t)m0 * Hs;    // uniform A base, phase H

  // ---- prologue: stage B tile0 -> Bs[0]; load A tile0 -> afA ----
  STAGE_B(0, wxh, vBX, 0);
  LOAD_A(afA, xb, vA0X, INs, 0);
  __syncthreads();

  // ---- phase X: t = 0..7 (tile t in Bs[t&1]; A set parity t&1) ----
  GSTEP(afA, afB, 0, wxh, vBX, 1 * 64, xb, vA0X, INs, 1 * 64);   // t=0
  GSTEP(afB, afA, 1, wxh, vBX, 2 * 64, xb, vA0X, INs, 2 * 64);   // t=1
  GSTEP(afA, afB, 0, wxh, vBX, 3 * 64, xb, vA0X, INs, 3 * 64);   // t=2
  GSTEP(afB, afA, 1, wxh, vBX, 4 * 64, xb, vA0X, INs, 4 * 64);   // t=3
  GSTEP(afA, afB, 0, wxh, vBX, 5 * 64, xb, vA0X, INs, 5 * 64);   // t=4
  GSTEP(afB, afA, 1, wxh, vBX, 6 * 64, xb, vA0X, INs, 6 * 64);   // t=5
  GSTEP(afA, afB, 0, wxh, vBX, 7 * 64, xb, vA0X, INs, 7 * 64);   // t=6
  GSTEP(afB, afA, 1, whh, vBH, 0,      hb, vA0H, Hs,  0);        // t=7 -> H tile0

  // ---- phase H: u = 8..23 (tile u in Bs[u&1]; A set parity u&1) ----
  GSTEP(afA, afB, 0, whh, vBH,  1 * 64, hb, vA0H, Hs,  1 * 64);  // u=8
  GSTEP(afB, afA, 1, whh, vBH,  2 * 64, hb, vA0H, Hs,  2 * 64);  // u=9
  GSTEP(afA, afB, 0, whh, vBH,  3 * 64, hb, vA0H, Hs,  3 * 64);  // u=10
  GSTEP(afB, afA, 1, whh, vBH,  4 * 64, hb, vA0H, Hs,  4 * 64);  // u=11
  GSTEP(afA, afB, 0, whh, vBH,  5 * 64, hb, vA0H, Hs,  5 * 64);  // u=12
  GSTEP(afB, afA, 1, whh, vBH,  6 * 64, hb, vA0H, Hs,  6 * 64);  // u=13
  GSTEP(afA, afB, 0, whh, vBH,  7 * 64, hb, vA0H, Hs,  7 * 64);  // u=14
  GSTEP(afB, afA, 1, whh, vBH,  8 * 64, hb, vA0H, Hs,  8 * 64);  // u=15
  GSTEP(afA, afB, 0, whh, vBH,  9 * 64, hb, vA0H, Hs,  9 * 64);  // u=16
  GSTEP(afB, afA, 1, whh, vBH, 10 * 64, hb, vA0H, Hs, 10 * 64);  // u=17
  GSTEP(afA, afB, 0, whh, vBH, 11 * 64, hb, vA0H, Hs, 11 * 64);  // u=18
  GSTEP(afB, afA, 1, whh, vBH, 12 * 64, hb, vA0H, Hs, 12 * 64);  // u=19
  GSTEP(afA, afB, 0, whh, vBH, 13 * 64, hb, vA0H, Hs, 13 * 64);  // u=20
  GSTEP(afB, afA, 1, whh, vBH, 14 * 64, hb, vA0H, Hs, 14 * 64);  // u=21
  GSTEP(afA, afB, 0, whh, vBH, 15 * 64, hb, vA0H, Hs, 15 * 64);  // u=22 -> tile23
  COMPUTE(1, afB);                                               // u=23 (no prefetch)

  // ---- fused epilogue: each thread owns ONE h and 16 batch rows ----
  const int h = h0 + wc * 16 + l15;
  const float bi  = biasp[h];
  const float bfv = biasp[Hs + h];
  const float bg  = biasp[2 * Hs + h];
  const float bo  = biasp[3 * Hs + h];
  const float sv = sp[h], tauv = taup[h];
  const float alphav = alphap[0], rhov = rhop[0], rh = 0.5f * rhov;
  const float rtau   = 1.0f / tauv;    // hoisted: one divide
  const float tworho = 2.0f / rhov;    // hoisted: one divide

  #pragma unroll
  for (int mt = 0; mt < 4; ++mt) {
    // 4 rows per (mt): one vector load instead of 4 scalar time loads
    const f32x4 t4 = *(const f32x4*)(timep + m0 + wr * 64 + mt * 16 + grp * 4);
    #pragma unroll
    for (int r = 0; r < 4; ++r) {
      // C/D layout (m89-verified): col = lane&15, row = grp*4 + reg
      const int brow = m0 + wr * 64 + mt * 16 + grp * 4 + r;
      // phi = fmod(tv-s, tau)/tau == q - trunc(q), q = (tv-s)/tau
      const float q   = (t4[r] - sv) * rtau;
      const float phi = q - truncf(q);
      const float kv  = phi < rh   ? phi * tworho
                      : (phi < rhov ? 2.0f - phi * tworho
                                    : alphav * phi);

      const float iv = acc[mt][0][r] + bi;
      const float fv = acc[mt][1][r] + bfv;
      const float gv = acc[mt][2][r] + bg;
      const float ov = acc[mt][3][r] + bo;
      const float cxv = cxp[(size_t)brow * Hs + h];
      const float ft = sigm(fv + 1.0f - kv);
      const float it2 = sigm(iv) * kv;
      const float gt = tanh_fast(gv) * kv;
      const float ot = sigm(ov) * kv;
      const float cy = ft * cxv + it2 * gt;
      const float hy = ot * tanh_fast(cy);

      outp[(size_t)brow * Hs + h] = hy;
      outp[(size_t)Bsz * Hs + (size_t)brow * Hs + h] = cy;
    }
  }
}

// Fallback (no usable ws): single kernel, fp32 converted during staging
// (r0 structure, 1-phase).
__global__ __launch_bounds__(256, 3)
void plstm_gemm_f32(const float* __restrict__ xin, const float* __restrict__ timep,
                    const float* __restrict__ hxp, const float* __restrict__ cxp,
                    const float* __restrict__ wxh, const float* __restrict__ biasp,
                    const float* __restrict__ whh, const float* __restrict__ taup,
                    const float* __restrict__ sp, const float* __restrict__ alphap,
                    const float* __restrict__ rhop, float* __restrict__ outp)
{
  __shared__ half_t Asf[BM * BK];
  __shared__ half_t Bsf[BM * BK];

  const int tid  = threadIdx.x;
  const int w    = tid >> 6;
  const int lane = tid & 63;
  const int l15  = lane & 15;
  const int grp  = lane >> 4;
  const int wr   = w >> 1;
  const int wc   = w & 1;

  const int m0 = blockIdx.x * BM;
  const int h0 = blockIdx.y * BH;

  f32x4 acc[4][4] = {};
  const int ldr = tid >> 3;
  const int ldc = tid & 7;
  const int NIT = INs / BK + Hs / BK;

  for (int it = 0; it < NIT; ++it) {
    const bool p1 = it >= INs / BK;
    const float* Ap = p1 ? hxp : xin;
    const float* Wp = p1 ? whh : wxh;
    const int Ka = p1 ? Hs : INs;
    const int k0 = (p1 ? (it - INs / BK) : it) * BK;
    #pragma unroll
    for (int i = 0; i < 4; ++i) {
      const int e    = i * 32 + ldr;
      const int gc8  = ldc ^ (e & 7);
      const int wrow = ((e >> 4) & 3) * Hs + h0 + ((e >> 6) << 4) + (e & 15);
      const float* ga = Ap + (size_t)(m0 + e) * Ka + (k0 + gc8 * 8);
      const f32x4 a0v = *(const f32x4*)ga, a1v = *(const f32x4*)(ga + 4);
      f16x8 pa;
      pa[0]=(half_t)a0v[0]; pa[1]=(half_t)a0v[1]; pa[2]=(half_t)a0v[2]; pa[3]=(half_t)a0v[3];
      pa[4]=(half_t)a1v[0]; pa[5]=(half_t)a1v[1]; pa[6]=(half_t)a1v[2]; pa[7]=(half_t)a1v[3];
      *(f16x8*)(Asf + (e * 8 + ldc) * 8) = pa;
      const float* gw = Wp + (size_t)wrow * Ka + (k0 + gc8 * 8);
      const f32x4 b0v = *(const f32x4*)gw, b1v = *(const f32x4*)(gw + 4);
      f16x8 pb;
      pb[0]=(half_t)b0v[0]; pb[1]=(half_t)b0v[1]; pb[2]=(half_t)b0v[2]; pb[3]=(half_t)b0v[3];
      pb[4]=(half_t)b1v[0]; pb[5]=(half_t)b1v[1]; pb[6]=(half_t)b1v[2]; pb[7]=(half_t)b1v[3];
      *(f16x8*)(Bsf + (e * 8 + ldc) * 8) = pb;
    }
    __syncthreads();
    #pragma unroll
    for (int kk = 0; kk < 2; ++kk) {
      const int c8x = kk * 4 + grp;
      f16x8 af[4], bfr[4];
      #pragma unroll
      for (int mt = 0; mt < 4; ++mt) {
        const int e = wr * 64 + mt * 16 + l15;
        af[mt] = *(const f16x8*)(Asf + (e * 8 + (c8x ^ (l15 & 7))) * 8);
      }
      #pragma unroll
      for (int nt = 0; nt < 4; ++nt) {
        const int e = wc * 64 + nt * 16 + l15;
        bfr[nt] = *(const f16x8*)(Bsf + (e * 8 + (c8x ^ (l15 & 7))) * 8);
      }
      #pragma unroll
      for (int mt = 0; mt < 4; ++mt)
        #pragma unroll
        for (int nt = 0; nt < 4; ++nt)
          acc[mt][nt] = __builtin_amdgcn_mfma_f32_16x16x32_f16(
              af[mt], bfr[nt], acc[mt][nt], 0, 0, 0);
    }
    __syncthreads();
  }

  const int h = h0 + wc * 16 + l15;
  const float bi  = biasp[h];
  const float bfv = biasp[Hs + h];
  const float bg  = biasp[2 * Hs + h];
  const float bo  = biasp[3 * Hs + h];
  const float sv = sp[h], tauv = taup[h];
  const float alphav = alphap[0], rhov = rhop[0], rh = 0.5f * rhov;
  const float rtau   = 1.0f / tauv;
  const float tworho = 2.0f / rhov;

  #pragma unroll
  for (int mt = 0; mt < 4; ++mt) {
    const f32x4 t4 = *(const f32x4*)(timep + m0 + wr * 64 + mt * 16 + grp * 4);
    #pragma unroll
    for (int r = 0; r < 4; ++r) {
      const int brow = m0 + wr * 64 + mt * 16 + grp * 4 + r;
      const float q   = (t4[r] - sv) * rtau;
      const float phi = q - truncf(q);
      const float kv  = phi < rh   ? phi * tworho
                      : (phi < rhov ? 2.0f - phi * tworho
                                    : alphav * phi);
      const float iv = acc[mt][0][r] + bi;
      const float fv = acc[mt][1][r] + bfv;
      const float gv = acc[mt][2][r] + bg;
      const float ov = acc[mt][3][r] + bo;
      const float cxv = cxp[(size_t)brow * Hs + h];
      const float ft = sigm(fv + 1.0f - kv);
      const float it2 = sigm(iv) * kv;
      const float gt = tanh_fast(gv) * kv;
      const float ot = sigm(ov) * kv;
      const float cy = ft * cxv + it2 * gt;
      const float hy = ot * tanh_fast(cy);
      outp[(size_t)brow * Hs + h] = hy;
      outp[(size_t)Bsz * Hs + (size_t)brow * Hs + h] = cy;
    }
  }
}

extern "C" void kernel_launch(void* const* d_in, const int* in_sizes, int n_in,
                              void* d_out, int out_size, void* d_ws, size_t ws_size,
                              hipStream_t stream) {
  (void)in_sizes; (void)n_in; (void)out_size;
  const float* xin   = (const float*)d_in[0];
  const float* timep = (const float*)d_in[1];
  const float* hxp   = (const float*)d_in[2];
  const float* cxp   = (const float*)d_in[3];
  const float* wxh   = (const float*)d_in[4];
  const float* biasp = (const float*)d_in[5];
  const float* whh   = (const float*)d_in[6];
  const float* taup  = (const float*)d_in[7];
  const float* sp    = (const float*)d_in[8];
  const float* alphap= (const float*)d_in[9];
  const float* rhop  = (const float*)d_in[10];
  float* outp = (float*)d_out;

  dim3 grid(Bsz / BM, Hs / BH);   // 32 x 32 = 1024 blocks = 4 per CU
  if (ws_size >= TOT * sizeof(half_t)) {
    half_t* ws = (half_t*)d_ws;
    cvt_kernel<<<(int)(TOT / 8 / 256), 256, 0, stream>>>(xin, hxp, wxh, whh, ws);
    plstm_gemm<<<grid, 256, 0, stream>>>(
        ws + OFF_X, ws + OFF_HX, cxp, ws + OFF_WX, biasp, ws + OFF_WH,
        timep, taup, sp, alphap, rhop, outp);
  } else {
    plstm_gemm_f32<<<grid, 256, 0, stream>>>(
        xin, timep, hxp, cxp, wxh, biasp, whh,
        taup, sp, alphap, rhop, outp);
  }
}

// Round 7
// 178.578 us; speedup vs baseline: 1.5284x; 1.5284x over previous
//
#include <hip/hip_runtime.h>

#define AS1 __attribute__((address_space(1)))
#define AS3 __attribute__((address_space(3)))

typedef _Float16 half_t;
typedef __attribute__((ext_vector_type(8))) _Float16 f16x8;  // 8 f16 = 4 VGPRs
typedef __attribute__((ext_vector_type(4))) float f32x4;

static constexpr int Bsz = 4096;   // batch
static constexpr int INs = 512;    // input features
static constexpr int Hs  = 1024;   // hidden
static constexpr int BM  = 128;    // batch rows per block
static constexpr int BH  = 32;     // h-cols per block (x4 gates = 128 eff cols)
static constexpr int BK  = 64;     // K-tile
static constexpr int NIT = INs / BK + Hs / BK;   // 8 + 16 = 24 K-iters

static constexpr size_t XN  = (size_t)Bsz * INs;
static constexpr size_t HXN = (size_t)Bsz * Hs;
static constexpr size_t WXN = (size_t)4 * Hs * INs;
static constexpr size_t WHN = (size_t)4 * Hs * Hs;
static constexpr size_t OFF_X  = 0;
static constexpr size_t OFF_HX = XN;
static constexpr size_t OFF_WX = XN + HXN;
static constexpr size_t OFF_WH = XN + HXN + WXN;
static constexpr size_t TOT    = XN + HXN + WXN + WHN;   // 12,582,912 f16

__device__ __forceinline__ float sigm(float x) {
  return 1.0f / (1.0f + __expf(-x));
}
__device__ __forceinline__ float tanh_fast(float x) {
  const float e = __expf(2.0f * x);
  return 1.0f - 2.0f / (e + 1.0f);
}

// fp32 -> fp16 (RNE) of the four matmul operands into ws. Loop-free;
// grid covers TOT/8 chunks exactly.
__global__ __launch_bounds__(256)
void cvt_kernel(const float* __restrict__ x, const float* __restrict__ hx,
                const float* __restrict__ wx, const float* __restrict__ wh,
                half_t* __restrict__ ws) {
  const size_t cid = (size_t)blockIdx.x * 256 + threadIdx.x;
  const size_t e = cid * 8;
  const float* src; size_t off;
  if (e < OFF_HX)      { src = x;  off = e - OFF_X; }
  else if (e < OFF_WX) { src = hx; off = e - OFF_HX; }
  else if (e < OFF_WH) { src = wx; off = e - OFF_WX; }
  else                 { src = wh; off = e - OFF_WH; }
  const f32x4 a = *(const f32x4*)(src + off);
  const f32x4 b = *(const f32x4*)(src + off + 4);
  f16x8 o;
  o[0]=(half_t)a[0]; o[1]=(half_t)a[1]; o[2]=(half_t)a[2]; o[3]=(half_t)a[3];
  o[4]=(half_t)b[0]; o[5]=(half_t)b[1]; o[6]=(half_t)b[2]; o[7]=(half_t)b[3];
  *(f16x8*)(ws + e) = o;
}

// ---------------------------------------------------------------------------
// r7 = r0 (best measured: 80.5 us GEMM) + two independent, low-risk deltas:
//  1. Bijective XCD swizzle for WEIGHT L2 locality. Default x-fastest
//     linearization + id%8 XCD round-robin gives each XCD blocks spanning
//     ALL 32 weight panels (12 MB >> 4 MB L2) -> weight staging streams
//     from L3 every K-step. Remap wg = 8q+k -> (x = q>>2, y = 4k+(q&3)):
//     XCD k owns y in [4k,4k+4) -> 4 weight panels = 1.5 MB, L2-resident,
//     re-read by 32 x-blocks from L2. nwg=1024 % 8 == 0 -> bijective.
//  2. r3's epilogue math (proven correct): fmodf+divides -> hoisted
//     rtau=1/tau, tworho=2/rho, phi = q-trunc(q); vectorized time load.
// K-loop body, LDS layout, staging, wave tiling: byte-identical to r0.
// ---------------------------------------------------------------------------
__global__ __launch_bounds__(256, 4)
void plstm_gemm(const half_t* __restrict__ xin,   // [B,IN]  f16
                const half_t* __restrict__ hxp,   // [B,H]   f16
                const float* __restrict__ cxp,    // [B,H]
                const half_t* __restrict__ wxh,   // [4H,IN] f16
                const float* __restrict__ biasp,  // [4H]
                const half_t* __restrict__ whh,   // [4H,H]  f16
                const float* __restrict__ timep,  // [B]
                const float* __restrict__ taup,   // [H]
                const float* __restrict__ sp,     // [H]
                const float* __restrict__ alphap, // [1]
                const float* __restrict__ rhop,   // [1]
                float* __restrict__ outp)         // [2,B,H] = hy ; cy
{
  // XOR-swizzled 16B-chunk layout: slot (row e, c8) holds global chunk c8^(e&7).
  __shared__ half_t As[BM * BK];    // 16 KB
  __shared__ half_t Bs[BM * BK];    // 16 KB

  const int tid  = threadIdx.x;
  const int w    = tid >> 6;
  const int lane = tid & 63;
  const int l15  = lane & 15;
  const int grp  = lane >> 4;
  const int wr   = w >> 1;
  const int wc   = w & 1;

  // XCD-locality swizzle (delta 1): wg = 8q+k -> bx = q>>2, by = 4k+(q&3)
  const int wg = blockIdx.x + (blockIdx.y << 5);
  const int xk = wg & 7;
  const int q  = wg >> 3;
  const int m0 = (q >> 2) * BM;
  const int h0 = ((xk << 2) + (q & 3)) * BH;

  f32x4 acc[4][4] = {};              // [m-subtile][gate]

  const int ldr = tid >> 3;          // 0..31
  const int ldc = tid & 7;           // 16B chunk col 0..7

  for (int it = 0; it < NIT; ++it) {
    const bool p1 = it >= INs / BK;
    const half_t* Ap = p1 ? hxp : xin;
    const half_t* Wp = p1 ? whh : wxh;
    const int Ka = p1 ? Hs : INs;
    const int k0 = (p1 ? (it - INs / BK) : it) * BK;
    #pragma unroll
    for (int i = 0; i < 4; ++i) {
      const int e    = i * 32 + ldr;
      const int gc8  = ldc ^ (e & 7);            // swizzle on global side
      const int wrow = ((e >> 4) & 3) * Hs + h0 + ((e >> 6) << 4) + (e & 15);
      const half_t* ga = Ap + (size_t)(m0 + e) * Ka + (k0 + gc8 * 8);
      __builtin_amdgcn_global_load_lds((AS1 void*)ga,
                                       (AS3 void*)(As + (e * 8 + ldc) * 8), 16, 0, 0);
      const half_t* gw = Wp + (size_t)wrow * Ka + (k0 + gc8 * 8);
      __builtin_amdgcn_global_load_lds((AS1 void*)gw,
                                       (AS3 void*)(Bs + (e * 8 + ldc) * 8), 16, 0, 0);
    }
    __syncthreads();

    #pragma unroll
    for (int kk = 0; kk < 2; ++kk) {
      const int c8x = kk * 4 + grp;
      f16x8 af[4], bfr[4];
      #pragma unroll
      for (int mt = 0; mt < 4; ++mt) {
        const int e = wr * 64 + mt * 16 + l15;   // e&7 == l15&7
        af[mt] = *(const f16x8*)(As + (e * 8 + (c8x ^ (l15 & 7))) * 8);
      }
      #pragma unroll
      for (int nt = 0; nt < 4; ++nt) {
        const int e = wc * 64 + nt * 16 + l15;
        bfr[nt] = *(const f16x8*)(Bs + (e * 8 + (c8x ^ (l15 & 7))) * 8);
      }
      #pragma unroll
      for (int mt = 0; mt < 4; ++mt)
        #pragma unroll
        for (int nt = 0; nt < 4; ++nt)
          acc[mt][nt] = __builtin_amdgcn_mfma_f32_16x16x32_f16(
              af[mt], bfr[nt], acc[mt][nt], 0, 0, 0);
    }
    __syncthreads();
  }

  // ---- fused epilogue (delta 2): each thread owns ONE h and 16 rows ----
  const int h = h0 + wc * 16 + l15;
  const float bi  = biasp[h];
  const float bfv = biasp[Hs + h];
  const float bg  = biasp[2 * Hs + h];
  const float bo  = biasp[3 * Hs + h];
  const float sv = sp[h], tauv = taup[h];
  const float alphav = alphap[0], rhov = rhop[0], rh = 0.5f * rhov;
  const float rtau   = 1.0f / tauv;    // hoisted: one divide
  const float tworho = 2.0f / rhov;    // hoisted: one divide

  #pragma unroll
  for (int mt = 0; mt < 4; ++mt) {
    const f32x4 t4 = *(const f32x4*)(timep + m0 + wr * 64 + mt * 16 + grp * 4);
    #pragma unroll
    for (int r = 0; r < 4; ++r) {
      // C/D layout (m89-verified): col = lane&15, row = grp*4 + reg
      const int brow = m0 + wr * 64 + mt * 16 + grp * 4 + r;
      // phi = fmod(tv-s, tau)/tau == q - trunc(q), q = (tv-s)/tau
      const float qv  = (t4[r] - sv) * rtau;
      const float phi = qv - truncf(qv);
      const float kv  = phi < rh   ? phi * tworho
                      : (phi < rhov ? 2.0f - phi * tworho
                                    : alphav * phi);

      const float iv = acc[mt][0][r] + bi;
      const float fv = acc[mt][1][r] + bfv;
      const float gv = acc[mt][2][r] + bg;
      const float ov = acc[mt][3][r] + bo;
      const float cxv = cxp[(size_t)brow * Hs + h];
      const float ft = sigm(fv + 1.0f - kv);
      const float it2 = sigm(iv) * kv;
      const float gt = tanh_fast(gv) * kv;
      const float ot = sigm(ov) * kv;
      const float cy = ft * cxv + it2 * gt;
      const float hy = ot * tanh_fast(cy);

      outp[(size_t)brow * Hs + h] = hy;
      outp[(size_t)Bsz * Hs + (size_t)brow * Hs + h] = cy;
    }
  }
}

// Fallback (no usable ws): single kernel, fp32 converted during staging
// (r0 structure, unchanged).
__global__ __launch_bounds__(256, 3)
void plstm_gemm_f32(const float* __restrict__ xin, const float* __restrict__ timep,
                    const float* __restrict__ hxp, const float* __restrict__ cxp,
                    const float* __restrict__ wxh, const float* __restrict__ biasp,
                    const float* __restrict__ whh, const float* __restrict__ taup,
                    const float* __restrict__ sp, const float* __restrict__ alphap,
                    const float* __restrict__ rhop, float* __restrict__ outp)
{
  __shared__ half_t As[BM * BK];
  __shared__ half_t Bs[BM * BK];

  const int tid  = threadIdx.x;
  const int w    = tid >> 6;
  const int lane = tid & 63;
  const int l15  = lane & 15;
  const int grp  = lane >> 4;
  const int wr   = w >> 1;
  const int wc   = w & 1;

  const int m0 = blockIdx.x * BM;
  const int h0 = blockIdx.y * BH;

  f32x4 acc[4][4] = {};
  const int ldr = tid >> 3;
  const int ldc = tid & 7;

  for (int it = 0; it < NIT; ++it) {
    const bool p1 = it >= INs / BK;
    const float* Ap = p1 ? hxp : xin;
    const float* Wp = p1 ? whh : wxh;
    const int Ka = p1 ? Hs : INs;
    const int k0 = (p1 ? (it - INs / BK) : it) * BK;
    #pragma unroll
    for (int i = 0; i < 4; ++i) {
      const int e    = i * 32 + ldr;
      const int gc8  = ldc ^ (e & 7);
      const int wrow = ((e >> 4) & 3) * Hs + h0 + ((e >> 6) << 4) + (e & 15);
      const float* ga = Ap + (size_t)(m0 + e) * Ka + (k0 + gc8 * 8);
      const f32x4 a0v = *(const f32x4*)ga, a1v = *(const f32x4*)(ga + 4);
      f16x8 pa;
      pa[0]=(half_t)a0v[0]; pa[1]=(half_t)a0v[1]; pa[2]=(half_t)a0v[2]; pa[3]=(half_t)a0v[3];
      pa[4]=(half_t)a1v[0]; pa[5]=(half_t)a1v[1]; pa[6]=(half_t)a1v[2]; pa[7]=(half_t)a1v[3];
      *(f16x8*)(As + (e * 8 + ldc) * 8) = pa;
      const float* gw = Wp + (size_t)wrow * Ka + (k0 + gc8 * 8);
      const f32x4 b0v = *(const f32x4*)gw, b1v = *(const f32x4*)(gw + 4);
      f16x8 pb;
      pb[0]=(half_t)b0v[0]; pb[1]=(half_t)b0v[1]; pb[2]=(half_t)b0v[2]; pb[3]=(half_t)b0v[3];
      pb[4]=(half_t)b1v[0]; pb[5]=(half_t)b1v[1]; pb[6]=(half_t)b1v[2]; pb[7]=(half_t)b1v[3];
      *(f16x8*)(Bs + (e * 8 + ldc) * 8) = pb;
    }
    __syncthreads();
    #pragma unroll
    for (int kk = 0; kk < 2; ++kk) {
      const int c8x = kk * 4 + grp;
      f16x8 af[4], bfr[4];
      #pragma unroll
      for (int mt = 0; mt < 4; ++mt) {
        const int e = wr * 64 + mt * 16 + l15;
        af[mt] = *(const f16x8*)(As + (e * 8 + (c8x ^ (l15 & 7))) * 8);
      }
      #pragma unroll
      for (int nt = 0; nt < 4; ++nt) {
        const int e = wc * 64 + nt * 16 + l15;
        bfr[nt] = *(const f16x8*)(Bs + (e * 8 + (c8x ^ (l15 & 7))) * 8);
      }
      #pragma unroll
      for (int mt = 0; mt < 4; ++mt)
        #pragma unroll
        for (int nt = 0; nt < 4; ++nt)
          acc[mt][nt] = __builtin_amdgcn_mfma_f32_16x16x32_f16(
              af[mt], bfr[nt], acc[mt][nt], 0, 0, 0);
    }
    __syncthreads();
  }

  const int h = h0 + wc * 16 + l15;
  const float bi  = biasp[h];
  const float bfv = biasp[Hs + h];
  const float bg  = biasp[2 * Hs + h];
  const float bo  = biasp[3 * Hs + h];
  const float sv = sp[h], tauv = taup[h];
  const float alphav = alphap[0], rhov = rhop[0], rh = 0.5f * rhov;
  const float rtau   = 1.0f / tauv;
  const float tworho = 2.0f / rhov;

  #pragma unroll
  for (int mt = 0; mt < 4; ++mt) {
    const f32x4 t4 = *(const f32x4*)(timep + m0 + wr * 64 + mt * 16 + grp * 4);
    #pragma unroll
    for (int r = 0; r < 4; ++r) {
      const int brow = m0 + wr * 64 + mt * 16 + grp * 4 + r;
      const float qv  = (t4[r] - sv) * rtau;
      const float phi = qv - truncf(qv);
      const float kv  = phi < rh   ? phi * tworho
                      : (phi < rhov ? 2.0f - phi * tworho
                                    : alphav * phi);
      const float iv = acc[mt][0][r] + bi;
      const float fv = acc[mt][1][r] + bfv;
      const float gv = acc[mt][2][r] + bg;
      const float ov = acc[mt][3][r] + bo;
      const float cxv = cxp[(size_t)brow * Hs + h];
      const float ft = sigm(fv + 1.0f - kv);
      const float it2 = sigm(iv) * kv;
      const float gt = tanh_fast(gv) * kv;
      const float ot = sigm(ov) * kv;
      const float cy = ft * cxv + it2 * gt;
      const float hy = ot * tanh_fast(cy);
      outp[(size_t)brow * Hs + h] = hy;
      outp[(size_t)Bsz * Hs + (size_t)brow * Hs + h] = cy;
    }
  }
}

extern "C" void kernel_launch(void* const* d_in, const int* in_sizes, int n_in,
                              void* d_out, int out_size, void* d_ws, size_t ws_size,
                              hipStream_t stream) {
  (void)in_sizes; (void)n_in; (void)out_size;
  const float* xin   = (const float*)d_in[0];
  const float* timep = (const float*)d_in[1];
  const float* hxp   = (const float*)d_in[2];
  const float* cxp   = (const float*)d_in[3];
  const float* wxh   = (const float*)d_in[4];
  const float* biasp = (const float*)d_in[5];
  const float* whh   = (const float*)d_in[6];
  const float* taup  = (const float*)d_in[7];
  const float* sp    = (const float*)d_in[8];
  const float* alphap= (const float*)d_in[9];
  const float* rhop  = (const float*)d_in[10];
  float* outp = (float*)d_out;

  dim3 grid(Bsz / BM, Hs / BH);   // 32 x 32 = 1024 blocks = 4 per CU
  if (ws_size >= TOT * sizeof(half_t)) {
    half_t* ws = (half_t*)d_ws;
    cvt_kernel<<<(int)(TOT / 8 / 256), 256, 0, stream>>>(xin, hxp, wxh, whh, ws);
    plstm_gemm<<<grid, 256, 0, stream>>>(
        ws + OFF_X, ws + OFF_HX, cxp, ws + OFF_WX, biasp, ws + OFF_WH,
        timep, taup, sp, alphap, rhop, outp);
  } else {
    plstm_gemm_f32<<<grid, 256, 0, stream>>>(
        xin, timep, hxp, cxp, wxh, biasp, whh,
        taup, sp, alphap, rhop, outp);
  }
}